// Round 1
// baseline (72.666 us; speedup 1.0000x reference)
//
#include <hip/hip_runtime.h>

#define BB 8
#define HH 256
#define WW 256
#define BHW (BB*HH*WW)
#define BIGV 512.0f

// ws layout:
//   [0, 4*BHW) floats            : g2 for 4 channels (0=x_fg,1=x_bg,2=y_fg,3=y_bg)
//   +4*BHW floats: 16 ints       : has_fg flags  (x: [0..7], y: [8..15])
//   after flags: BB*HH floats    : per-row partial sums

__global__ __launch_bounds__(256) void edt_cols(const float* __restrict__ x,
                                                const float* __restrict__ y,
                                                float* __restrict__ g2,
                                                int* __restrict__ flags) {
    int tid = blockIdx.x * blockDim.x + threadIdx.x;   // 4096 threads
    int w  = tid & (WW - 1);
    int b  = (tid >> 8) & 7;
    int ip = tid >> 11;                                 // 0 = x, 1 = y
    const float* src = (ip ? y : x) + (size_t)b * HH * WW + w;
    float* gf = g2 + (size_t)(ip * 2 + 0) * BHW + (size_t)b * HH * WW + w;
    float* gb = g2 + (size_t)(ip * 2 + 1) * BHW + (size_t)b * HH * WW + w;

    float df = BIGV, db = BIGV;
    bool anyfg = false;
    for (int i = 0; i < HH; ++i) {
        bool m = src[i * WW] > 0.5f;
        anyfg |= m;
        df = m ? fminf(df + 1.0f, BIGV) : 0.0f;
        db = m ? 0.0f : fminf(db + 1.0f, BIGV);
        gf[i * WW] = df;
        gb[i * WW] = db;
    }
    df = BIGV; db = BIGV;
    for (int i = HH - 1; i >= 0; --i) {
        bool m = src[i * WW] > 0.5f;
        df = m ? fminf(df + 1.0f, BIGV) : 0.0f;
        db = m ? 0.0f : fminf(db + 1.0f, BIGV);
        float vf = fminf(gf[i * WW], df);
        float vb = fminf(gb[i * WW], db);
        gf[i * WW] = vf * vf;
        gb[i * WW] = vb * vb;
    }
    if (anyfg) flags[ip * 8 + b] = 1;   // benign race: all writers store 1
}

__global__ __launch_bounds__(256) void row_pass(const float* __restrict__ x,
                                                const float* __restrict__ y,
                                                const float* __restrict__ g2,
                                                const int* __restrict__ flags,
                                                float* __restrict__ partials) {
    __shared__ float s0[WW], s1[WW], s2[WW], s3[WW];
    __shared__ float wsum[4];
    int bh = blockIdx.x;          // b*HH + h
    int b  = bh >> 8;
    int j  = threadIdx.x;
    size_t rowoff = (size_t)bh * WW;

    float xv = x[rowoff + j];
    float yv = y[rowoff + j];
    s0[j] = g2[0 * (size_t)BHW + rowoff + j];
    s1[j] = g2[1 * (size_t)BHW + rowoff + j];
    s2[j] = g2[2 * (size_t)BHW + rowoff + j];
    s3[j] = g2[3 * (size_t)BHW + rowoff + j];
    __syncthreads();

    float b0 = 3e38f, b1 = 3e38f, b2 = 3e38f, b3 = 3e38f;
    float dj = (float)j;
    #pragma unroll 8
    for (int jp = 0; jp < WW; ++jp) {
        float d2 = dj * dj;               // exact: |dj| <= 255
        b0 = fminf(b0, d2 + s0[jp]);      // LDS broadcast: all lanes same jp
        b1 = fminf(b1, d2 + s1[jp]);
        b2 = fminf(b2, d2 + s2[jp]);
        b3 = fminf(b3, d2 + s3[jp]);
        dj -= 1.0f;
    }

    float dtx = flags[b]     ? (sqrtf(b0) + sqrtf(b1)) : 0.0f;
    float dty = flags[8 + b] ? (sqrtf(b2) + sqrtf(b3)) : 0.0f;
    float e = xv - yv;
    float val = e * e * (dtx * dtx + dty * dty);

    for (int off = 32; off; off >>= 1) val += __shfl_down(val, off, 64);
    int lane = j & 63, wv = j >> 6;
    if (lane == 0) wsum[wv] = val;
    __syncthreads();
    if (j == 0) partials[bh] = wsum[0] + wsum[1] + wsum[2] + wsum[3];
}

__global__ __launch_bounds__(256) void final_reduce(const float* __restrict__ partials,
                                                    float* __restrict__ out) {
    __shared__ float wsum[4];
    int j = threadIdx.x;
    float s = 0.0f;
    for (int i = j; i < BB * HH; i += 256) s += partials[i];
    for (int off = 32; off; off >>= 1) s += __shfl_down(s, off, 64);
    if ((j & 63) == 0) wsum[j >> 6] = s;
    __syncthreads();
    if (j == 0) out[0] = (wsum[0] + wsum[1] + wsum[2] + wsum[3]) * (1.0f / (float)BHW);
}

extern "C" void kernel_launch(void* const* d_in, const int* in_sizes, int n_in,
                              void* d_out, int out_size, void* d_ws, size_t ws_size,
                              hipStream_t stream) {
    const float* x = (const float*)d_in[0];
    const float* y = (const float*)d_in[1];
    float* out = (float*)d_out;

    char* ws = (char*)d_ws;
    float* g2      = (float*)ws;                                  // 4*BHW floats
    int*   flags   = (int*)(ws + (size_t)4 * BHW * sizeof(float));  // 16 ints
    float* partials = (float*)(ws + (size_t)4 * BHW * sizeof(float) + 16 * sizeof(int));

    hipMemsetAsync(flags, 0, 16 * sizeof(int), stream);

    edt_cols<<<16, 256, 0, stream>>>(x, y, g2, flags);
    row_pass<<<BB * HH, 256, 0, stream>>>(x, y, g2, flags, partials);
    final_reduce<<<1, 256, 0, stream>>>(partials, out);
}

// Round 2
// 24.328 us; speedup vs baseline: 2.9869x; 2.9869x over previous
//
#include <hip/hip_runtime.h>

#define BB 8
#define HH 256
#define WW 256
#define BHW (BB*HH*WW)
#define BIGV 512.0f

// ws layout:
//   [0, 4*BHW) floats : g2 for 4 channels (0=x_fg,1=x_bg,2=y_fg,3=y_bg)
//   +4*BHW floats     : 16 ints has_fg flags (x: [0..7], y: [8..15])
//   after flags       : BB*HH floats per-row partial sums

// Vertical EDT via min-plus segmented scan.
// grid = 2(input) * 8(batch) * 16(col tile) = 256 blocks, 256 threads.
// thread: c = t&15 (column in tile), s = t>>4 (16-row segment).
__global__ __launch_bounds__(256) void edt_vert(const float* __restrict__ x,
                                                const float* __restrict__ y,
                                                float* __restrict__ g2,
                                                int* __restrict__ flags) {
    __shared__ float Cf[2][16][16];   // [ch][seg][col]: dist from seg END to last zero (1e9 if none)
    __shared__ float Cb[2][16][16];   // [ch][seg][col]: dist from seg START to first zero

    int blk = blockIdx.x;
    int tileIdx = blk & 15;
    int b  = (blk >> 4) & 7;
    int ip = blk >> 7;
    int t = threadIdx.x;
    int c = t & 15, s = t >> 4;

    const float* src = (ip ? y : x) + (size_t)b*HH*WW + tileIdx*16 + c;

    // Load this thread's 16 rows once; keep only mask bits.
    unsigned m = 0;
    const float* p = src + (size_t)(s*16)*WW;
    #pragma unroll
    for (int i = 0; i < 16; ++i) {
        if (p[(size_t)i*WW] > 0.5f) m |= (1u << i);
    }

    // Segment summaries. fg zeros where bit clear; bg zeros where bit set.
    unsigned invm = (~m) & 0xFFFFu;
    float cf0 = invm ? (float)(15 - (31 - __clz((int)invm))) : 1e9f;
    float cb0 = invm ? (float)(__ffs((int)invm) - 1)          : 1e9f;
    float cf1 = m    ? (float)(15 - (31 - __clz((int)m)))     : 1e9f;
    float cb1 = m    ? (float)(__ffs((int)m) - 1)             : 1e9f;
    Cf[0][s][c] = cf0;  Cb[0][s][c] = cb0;
    Cf[1][s][c] = cf1;  Cb[1][s][c] = cb1;
    __syncthreads();

    // Carries entering this segment (16 short LDS loops).
    float ef[2], eb[2];
    #pragma unroll
    for (int ch = 0; ch < 2; ++ch) {
        float e = BIGV;
        for (int sp = 0; sp < s; ++sp)
            e = fminf(fminf(e + 16.0f, BIGV), Cf[ch][sp][c]);
        ef[ch] = e;
        e = BIGV;
        for (int sp = 15; sp > s; --sp)
            e = fminf(fminf(e + 16.0f, BIGV), Cb[ch][sp][c]);
        eb[ch] = e;
    }

    // Exact detail pass in registers, write g^2.
    size_t base0 = (size_t)(ip*2+0)*BHW + (size_t)b*HH*WW + tileIdx*16 + c;
    size_t base1 = (size_t)(ip*2+1)*BHW + (size_t)b*HH*WW + tileIdx*16 + c;
    #pragma unroll
    for (int ch = 0; ch < 2; ++ch) {
        float bwdv[16];
        float d = eb[ch];
        #pragma unroll
        for (int i = 15; i >= 0; --i) {
            bool z = ch ? (((m >> i) & 1u) != 0u) : (((m >> i) & 1u) == 0u);
            d = z ? 0.0f : fminf(d + 1.0f, BIGV);
            bwdv[i] = d;
        }
        d = ef[ch];
        size_t base = ch ? base1 : base0;
        #pragma unroll
        for (int i = 0; i < 16; ++i) {
            bool z = ch ? (((m >> i) & 1u) != 0u) : (((m >> i) & 1u) == 0u);
            d = z ? 0.0f : fminf(d + 1.0f, BIGV);
            float g = fminf(d, bwdv[i]);
            g2[base + (size_t)(s*16 + i)*WW] = g * g;
        }
    }
    if (m) flags[ip*8 + b] = 1;   // benign race: all writers store 1
}

// Horizontal pass with outward early-exit search + fused loss + row reduce.
__global__ __launch_bounds__(256) void row_pass(const float* __restrict__ x,
                                                const float* __restrict__ y,
                                                const float* __restrict__ g2,
                                                const int* __restrict__ flags,
                                                float* __restrict__ partials) {
    __shared__ float sp0[768], sp1[768], sp2[768], sp3[768];
    __shared__ float wsum[4];
    int bh = blockIdx.x;          // b*HH + h
    int b  = bh >> 8;
    int j  = threadIdx.x;
    size_t rowoff = (size_t)bh * WW;

    float xv = x[rowoff + j];
    float yv = y[rowoff + j];
    sp0[j] = 1e9f; sp1[j] = 1e9f; sp2[j] = 1e9f; sp3[j] = 1e9f;
    sp0[j+512] = 1e9f; sp1[j+512] = 1e9f; sp2[j+512] = 1e9f; sp3[j+512] = 1e9f;
    sp0[j+256] = g2[0*(size_t)BHW + rowoff + j];
    sp1[j+256] = g2[1*(size_t)BHW + rowoff + j];
    sp2[j+256] = g2[2*(size_t)BHW + rowoff + j];
    sp3[j+256] = g2[3*(size_t)BHW + rowoff + j];
    __syncthreads();

    float b0 = sp0[j+256], b1 = sp1[j+256], b2 = sp2[j+256], b3 = sp3[j+256];
    for (int dl = 1; dl < 256; ++dl) {
        float d2 = (float)(dl * dl);
        float bmax = fmaxf(fmaxf(b0, b1), fmaxf(b2, b3));
        if (!__any(d2 < bmax)) break;     // no candidate can improve any lane
        int l = j + 256 - dl, r = j + 256 + dl;
        b0 = fminf(b0, fminf(d2 + sp0[l], d2 + sp0[r]));
        b1 = fminf(b1, fminf(d2 + sp1[l], d2 + sp1[r]));
        b2 = fminf(b2, fminf(d2 + sp2[l], d2 + sp2[r]));
        b3 = fminf(b3, fminf(d2 + sp3[l], d2 + sp3[r]));
    }

    float dtx = flags[b]     ? (sqrtf(b0) + sqrtf(b1)) : 0.0f;
    float dty = flags[8 + b] ? (sqrtf(b2) + sqrtf(b3)) : 0.0f;
    float e = xv - yv;
    float val = e * e * (dtx * dtx + dty * dty);

    for (int off = 32; off; off >>= 1) val += __shfl_down(val, off, 64);
    if ((j & 63) == 0) wsum[j >> 6] = val;
    __syncthreads();
    if (j == 0) partials[bh] = wsum[0] + wsum[1] + wsum[2] + wsum[3];
}

__global__ __launch_bounds__(256) void final_reduce(const float* __restrict__ partials,
                                                    float* __restrict__ out) {
    __shared__ float wsum[4];
    int j = threadIdx.x;
    float s = 0.0f;
    for (int i = j; i < BB * HH; i += 256) s += partials[i];
    for (int off = 32; off; off >>= 1) s += __shfl_down(s, off, 64);
    if ((j & 63) == 0) wsum[j >> 6] = s;
    __syncthreads();
    if (j == 0) out[0] = (wsum[0] + wsum[1] + wsum[2] + wsum[3]) * (1.0f / (float)BHW);
}

extern "C" void kernel_launch(void* const* d_in, const int* in_sizes, int n_in,
                              void* d_out, int out_size, void* d_ws, size_t ws_size,
                              hipStream_t stream) {
    const float* x = (const float*)d_in[0];
    const float* y = (const float*)d_in[1];
    float* out = (float*)d_out;

    char* ws = (char*)d_ws;
    float* g2       = (float*)ws;                                      // 4*BHW floats
    int*   flags    = (int*)(ws + (size_t)4 * BHW * sizeof(float));    // 16 ints
    float* partials = (float*)(ws + (size_t)4 * BHW * sizeof(float) + 16 * sizeof(int));

    hipMemsetAsync(flags, 0, 16 * sizeof(int), stream);

    edt_vert<<<256, 256, 0, stream>>>(x, y, g2, flags);
    row_pass<<<BB * HH, 256, 0, stream>>>(x, y, g2, flags, partials);
    final_reduce<<<1, 256, 0, stream>>>(partials, out);
}